// Round 2
// baseline (226.525 us; speedup 1.0000x reference)
//
#include <hip/hip_runtime.h>

// HierarchicalClassifier: B=16384, D=2048, N_TOP=8, N_CLASS=16
// out[b, t*16+c] = sigmoid(f.top_W[t]+top_b[t]) * softmax_c(f.bottom_W[t,:,c]+bot_b[t,c])
//
// R8: occupancy doubling. R7 post-mortem: source-level deep pipelining was
// neutral (compiler already schedules the barrier-free loop optimally), so
// ILP is maxed; the kernel is latency-bound at 2 waves/SIMD (LDS 74KB ->
// 2 blocks/CU; ~235 VGPR). Fix: one row-tile per wave (M_ROWS 16), so
// acc 72->36 VGPR, LDS 74->38KB, grid 512->1024 blocks, launch_bounds(256,4)
// -> 4 blocks/CU = 4 waves/SIMD = 2x latency hiding. B is single-buffered
// (~110 VGPR total, no spill at the 128 cap); compiler hoists next-step B
// loads into the freed registers on its own (R7 lesson). K-split stays 4-way
// with identical per-wave K order -> bit-identical numerics to R6/R7.

#define D_DIM 2048
#define NTILE 9          // 144 columns / 16
#define M_ROWS 16        // rows per workgroup (1 row-tile)

using f32x4 = float __attribute__((ext_vector_type(4)));
using half8 = _Float16 __attribute__((ext_vector_type(8)));
using fp16x2 = __fp16 __attribute__((ext_vector_type(2)));

// Swizzled B layout: S[(((w*16 + ks)*9 + nt)*64 + lane)*8 + j]
//   = W[n = nt*16 + (lane&15)][k = w*512 + ks*32 + (lane>>4)*8 + j]
// W rows 0..7 = top_W, 8..135 = bottom_W[t][:,c] (n-8 = t*16+c), 136..143 = 0.
__global__ void prep_weights(const float* __restrict__ topW,
                             const float* __restrict__ botW,
                             _Float16* __restrict__ S) {
    int idx = blockIdx.x * blockDim.x + threadIdx.x;   // [0, 4*16*9*64)
    if (idx >= 4 * 16 * NTILE * 64) return;
    int lane = idx & 63;
    int tmp  = idx >> 6;          // (w*16+ks)*9 + nt
    int nt   = tmp % NTILE;
    int wks  = tmp / NTILE;       // w*16+ks in [0,64)
    int n     = nt * 16 + (lane & 15);
    int kbase = wks * 32 + (lane >> 4) * 8;

    _Float16 v[8];
    #pragma unroll
    for (int j = 0; j < 8; j++) {
        int k = kbase + j;
        float x = 0.0f;
        if (n < 8) {
            x = topW[n * D_DIM + k];
        } else if (n < 136) {
            int t = (n - 8) >> 4, c = (n - 8) & 15;
            x = botW[(t * D_DIM + k) * 16 + c];
        }
        v[j] = (_Float16)x;
    }
    *(half8*)(S + (size_t)idx * 8) = *(half8*)v;
}

static __device__ __forceinline__ half8 pack_af(f32x4 a, f32x4 b) {
    fp16x2 p0 = __builtin_amdgcn_cvt_pkrtz(a[0], a[1]);
    fp16x2 p1 = __builtin_amdgcn_cvt_pkrtz(a[2], a[3]);
    fp16x2 p2 = __builtin_amdgcn_cvt_pkrtz(b[0], b[1]);
    fp16x2 p3 = __builtin_amdgcn_cvt_pkrtz(b[2], b[3]);
    half8 r;
    r[0] = (_Float16)p0[0]; r[1] = (_Float16)p0[1];
    r[2] = (_Float16)p1[0]; r[3] = (_Float16)p1[1];
    r[4] = (_Float16)p2[0]; r[5] = (_Float16)p2[1];
    r[6] = (_Float16)p3[0]; r[7] = (_Float16)p3[1];
    return r;
}

__global__ __launch_bounds__(256, 4) void hc_fused(
        const float* __restrict__ feat, const _Float16* __restrict__ Bsw,
        const float* __restrict__ top_b, const float* __restrict__ bot_b,
        float* __restrict__ out) {
    __shared__ float red[4][M_ROWS][148];   // [wave][row][ncol(+pad)] = 37.9 KB

    const int tid  = threadIdx.x;
    const int lane = tid & 63, wave = tid >> 6;
    const int quad = lane >> 4, low = lane & 15;
    const size_t row0 = (size_t)blockIdx.x * M_ROWS;

    // A: lane holds A[m=low][k = quad*8 + j]; this wave's K range = [wave*512, +512)
    const float* A0 = feat + (row0 + low) * D_DIM + wave * 512 + quad * 8;
    // B: swizzled fragment stream; per (ks,nt) a contiguous 1KB wave read.
    const _Float16* Bp = Bsw + (size_t)wave * (16 * NTILE * 512) + lane * 8;

    f32x4 acc[NTILE];
    #pragma unroll
    for (int i = 0; i < NTILE; i++) acc[i] = (f32x4)0.0f;

    // A double-buffered in registers; B single-buffered per step (locals die
    // each step; compiler hoists next-step B loads into the free regs).
    f32x4 aC0, aC1, aN0, aN1;
    aC0 = *(const f32x4*)(A0);
    aC1 = *(const f32x4*)(A0 + 4);

#define STEP(KS, AL0, AL1, NL0, NL1) do {                                  \
        const _Float16* Bn_ = Bp + (size_t)(KS) * NTILE * 512;             \
        half8 b0_ = *(const half8*)(Bn_);                                  \
        half8 b1_ = *(const half8*)(Bn_ + 1 * 512);                        \
        half8 b2_ = *(const half8*)(Bn_ + 2 * 512);                        \
        half8 b3_ = *(const half8*)(Bn_ + 3 * 512);                        \
        half8 b4_ = *(const half8*)(Bn_ + 4 * 512);                        \
        half8 b5_ = *(const half8*)(Bn_ + 5 * 512);                        \
        half8 b6_ = *(const half8*)(Bn_ + 6 * 512);                        \
        half8 b7_ = *(const half8*)(Bn_ + 7 * 512);                        \
        half8 b8_ = *(const half8*)(Bn_ + 8 * 512);                        \
        if ((KS) < 15) {                                                   \
            NL0 = *(const f32x4*)(A0 + ((KS) + 1) * 32);                   \
            NL1 = *(const f32x4*)(A0 + ((KS) + 1) * 32 + 4);               \
        }                                                                  \
        const half8 af_ = pack_af(AL0, AL1);                               \
        acc[0] = __builtin_amdgcn_mfma_f32_16x16x32_f16(af_, b0_, acc[0], 0, 0, 0); \
        acc[1] = __builtin_amdgcn_mfma_f32_16x16x32_f16(af_, b1_, acc[1], 0, 0, 0); \
        acc[2] = __builtin_amdgcn_mfma_f32_16x16x32_f16(af_, b2_, acc[2], 0, 0, 0); \
        acc[3] = __builtin_amdgcn_mfma_f32_16x16x32_f16(af_, b3_, acc[3], 0, 0, 0); \
        acc[4] = __builtin_amdgcn_mfma_f32_16x16x32_f16(af_, b4_, acc[4], 0, 0, 0); \
        acc[5] = __builtin_amdgcn_mfma_f32_16x16x32_f16(af_, b5_, acc[5], 0, 0, 0); \
        acc[6] = __builtin_amdgcn_mfma_f32_16x16x32_f16(af_, b6_, acc[6], 0, 0, 0); \
        acc[7] = __builtin_amdgcn_mfma_f32_16x16x32_f16(af_, b7_, acc[7], 0, 0, 0); \
        acc[8] = __builtin_amdgcn_mfma_f32_16x16x32_f16(af_, b8_, acc[8], 0, 0, 0); \
    } while (0)

    STEP( 0, aC0, aC1, aN0, aN1);
    STEP( 1, aN0, aN1, aC0, aC1);
    STEP( 2, aC0, aC1, aN0, aN1);
    STEP( 3, aN0, aN1, aC0, aC1);
    STEP( 4, aC0, aC1, aN0, aN1);
    STEP( 5, aN0, aN1, aC0, aC1);
    STEP( 6, aC0, aC1, aN0, aN1);
    STEP( 7, aN0, aN1, aC0, aC1);
    STEP( 8, aC0, aC1, aN0, aN1);
    STEP( 9, aN0, aN1, aC0, aC1);
    STEP(10, aC0, aC1, aN0, aN1);
    STEP(11, aN0, aN1, aC0, aC1);
    STEP(12, aC0, aC1, aN0, aN1);
    STEP(13, aN0, aN1, aC0, aC1);
    STEP(14, aC0, aC1, aN0, aN1);
    STEP(15, aN0, aN1, aC0, aC1);
#undef STEP

    // C/D layout (measured m89/m91): col = lane&15, row = quad*4 + reg.
    #pragma unroll
    for (int nt = 0; nt < NTILE; nt++) {
        #pragma unroll
        for (int r = 0; r < 4; r++) {
            red[wave][quad * 4 + r][nt * 16 + low] = acc[nt][r];
        }
    }
    __syncthreads();

    // Epilogue: threads 0..127 -> (row = tid>>3 in [0,16), top = tid&7).
    if (tid < 128) {
        const int row = tid >> 3;
        const int top = tid & 7;

        float zt = top_b[top];
        #pragma unroll
        for (int w = 0; w < 4; w++) zt += red[w][row][top];
        const float sig = 1.0f / (1.0f + __expf(-zt));

        float z[16];
        float zmax = -1e30f;
        #pragma unroll
        for (int c = 0; c < 16; c++) {
            float v = bot_b[top * 16 + c];
            #pragma unroll
            for (int w = 0; w < 4; w++) v += red[w][row][8 + top * 16 + c];
            z[c] = v;
            zmax = fmaxf(zmax, v);
        }
        float s = 0.0f;
        #pragma unroll
        for (int c = 0; c < 16; c++) { z[c] = __expf(z[c] - zmax); s += z[c]; }
        const float scale = sig / s;

        float* o = out + (row0 + row) * 128 + top * 16;
        #pragma unroll
        for (int c = 0; c < 16; c += 4) {
            f32x4 v = { z[c] * scale, z[c+1] * scale, z[c+2] * scale, z[c+3] * scale };
            *(f32x4*)(o + c) = v;
        }
    }
}

extern "C" void kernel_launch(void* const* d_in, const int* in_sizes, int n_in,
                              void* d_out, int out_size, void* d_ws, size_t ws_size,
                              hipStream_t stream) {
    const float* feat  = (const float*)d_in[0];   // (16384, 2048)
    const float* topW  = (const float*)d_in[1];   // (8, 2048)
    const float* topB  = (const float*)d_in[2];   // (8,)
    const float* botW  = (const float*)d_in[3];   // (8, 2048, 16)
    const float* botB  = (const float*)d_in[4];   // (8, 16)
    float* out = (float*)d_out;                   // (16384, 128)
    _Float16* Bsw = (_Float16*)d_ws;              // 144*2048 fp16 = 576 KB swizzled

    prep_weights<<<(4 * 16 * NTILE * 64 + 255) / 256, 256, 0, stream>>>(topW, botW, Bsw);
    hc_fused<<<16384 / M_ROWS, 256, 0, stream>>>(feat, Bsw, topB, botB, out);
}

// Round 3
// 217.767 us; speedup vs baseline: 1.0402x; 1.0402x over previous
//
#include <hip/hip_runtime.h>

// HierarchicalClassifier: B=16384, D=2048, N_TOP=8, N_CLASS=16
// out[b, t*16+c] = sigmoid(f.top_W[t]+top_b[t]) * softmax_c(f.bottom_W[t,:,c]+bot_b[t,c])
//
// R9: barrier-clamped software pipeline. R8 counters (VGPR=52, MfmaUtil 4.5%,
// VALUBusy 3.1%, HBM 12.6%, dur invariant to L3-residency) prove the compiler
// sank all B loads to just-before-use -> per-load L2 round-trip serialization,
// pure latency-bound. R7 proved source-order pipelining is ignored. Forcing
// device: per-K-step __syncthreads(). hipcc emits s_waitcnt vmcnt(0) before
// s_barrier (m97 evidence) and never moves memory ops across it, so the
// schedule {compute from last step's regs -> issue next step's B+A -> barrier}
// guarantees loads complete a full step before use; the drain bubble overlaps
// across 4 blocks/CU (red=37.9KB LDS). B issued AFTER compute reuses the same
// 36 VGPRs (no double buffer): forced-live ~100 VGPR -> (256,4) holds,
// 16 waves/CU. K order unchanged -> bit-identical numerics.

#define D_DIM 2048
#define NTILE 9          // 144 columns / 16
#define M_ROWS 16        // rows per workgroup (1 row-tile)

using f32x4 = float __attribute__((ext_vector_type(4)));
using half8 = _Float16 __attribute__((ext_vector_type(8)));
using fp16x2 = __fp16 __attribute__((ext_vector_type(2)));

// Swizzled B layout: S[(((w*16 + ks)*9 + nt)*64 + lane)*8 + j]
//   = W[n = nt*16 + (lane&15)][k = w*512 + ks*32 + (lane>>4)*8 + j]
// W rows 0..7 = top_W, 8..135 = bottom_W[t][:,c] (n-8 = t*16+c), 136..143 = 0.
__global__ void prep_weights(const float* __restrict__ topW,
                             const float* __restrict__ botW,
                             _Float16* __restrict__ S) {
    int idx = blockIdx.x * blockDim.x + threadIdx.x;   // [0, 4*16*9*64)
    if (idx >= 4 * 16 * NTILE * 64) return;
    int lane = idx & 63;
    int tmp  = idx >> 6;          // (w*16+ks)*9 + nt
    int nt   = tmp % NTILE;
    int wks  = tmp / NTILE;       // w*16+ks in [0,64)
    int n     = nt * 16 + (lane & 15);
    int kbase = wks * 32 + (lane >> 4) * 8;

    _Float16 v[8];
    #pragma unroll
    for (int j = 0; j < 8; j++) {
        int k = kbase + j;
        float x = 0.0f;
        if (n < 8) {
            x = topW[n * D_DIM + k];
        } else if (n < 136) {
            int t = (n - 8) >> 4, c = (n - 8) & 15;
            x = botW[(t * D_DIM + k) * 16 + c];
        }
        v[j] = (_Float16)x;
    }
    *(half8*)(S + (size_t)idx * 8) = *(half8*)v;
}

static __device__ __forceinline__ half8 pack_af(f32x4 a, f32x4 b) {
    fp16x2 p0 = __builtin_amdgcn_cvt_pkrtz(a[0], a[1]);
    fp16x2 p1 = __builtin_amdgcn_cvt_pkrtz(a[2], a[3]);
    fp16x2 p2 = __builtin_amdgcn_cvt_pkrtz(b[0], b[1]);
    fp16x2 p3 = __builtin_amdgcn_cvt_pkrtz(b[2], b[3]);
    half8 r;
    r[0] = (_Float16)p0[0]; r[1] = (_Float16)p0[1];
    r[2] = (_Float16)p1[0]; r[3] = (_Float16)p1[1];
    r[4] = (_Float16)p2[0]; r[5] = (_Float16)p2[1];
    r[6] = (_Float16)p3[0]; r[7] = (_Float16)p3[1];
    return r;
}

__global__ __launch_bounds__(256, 4) void hc_fused(
        const float* __restrict__ feat, const _Float16* __restrict__ Bsw,
        const float* __restrict__ top_b, const float* __restrict__ bot_b,
        float* __restrict__ out) {
    __shared__ float red[4][M_ROWS][148];   // [wave][row][ncol(+pad)] = 37.9 KB

    const int tid  = threadIdx.x;
    const int lane = tid & 63, wave = tid >> 6;
    const int quad = lane >> 4, low = lane & 15;
    const size_t row0 = (size_t)blockIdx.x * M_ROWS;

    // A: lane holds A[m=low][k = quad*8 + j]; this wave's K range = [wave*512, +512)
    const float* A0 = feat + (row0 + low) * D_DIM + wave * 512 + quad * 8;
    // B: swizzled fragment stream; per (ks,nt) a contiguous 1KB wave read.
    const _Float16* Bp = Bsw + (size_t)wave * (16 * NTILE * 512) + lane * 8;

    f32x4 acc[NTILE];
    #pragma unroll
    for (int i = 0; i < NTILE; i++) acc[i] = (f32x4)0.0f;

    // Single set of named B regs (reloaded after each compute -> WAR reuse,
    // no double buffer) + A double-buffered. All loads complete by the
    // barrier drain at step end -> compute never waits on memory.
    half8 b0_, b1_, b2_, b3_, b4_, b5_, b6_, b7_, b8_;
    f32x4 aC0, aC1, aN0, aN1;

    // Prologue: load step 0, drain, lockstep.
    b0_ = *(const half8*)(Bp);
    b1_ = *(const half8*)(Bp + 1 * 512);
    b2_ = *(const half8*)(Bp + 2 * 512);
    b3_ = *(const half8*)(Bp + 3 * 512);
    b4_ = *(const half8*)(Bp + 4 * 512);
    b5_ = *(const half8*)(Bp + 5 * 512);
    b6_ = *(const half8*)(Bp + 6 * 512);
    b7_ = *(const half8*)(Bp + 7 * 512);
    b8_ = *(const half8*)(Bp + 8 * 512);
    aC0 = *(const f32x4*)(A0);
    aC1 = *(const f32x4*)(A0 + 4);
    __syncthreads();

#define STEP(KS, AL0, AL1, NL0, NL1) do {                                  \
        const half8 af_ = pack_af(AL0, AL1);                               \
        acc[0] = __builtin_amdgcn_mfma_f32_16x16x32_f16(af_, b0_, acc[0], 0, 0, 0); \
        acc[1] = __builtin_amdgcn_mfma_f32_16x16x32_f16(af_, b1_, acc[1], 0, 0, 0); \
        acc[2] = __builtin_amdgcn_mfma_f32_16x16x32_f16(af_, b2_, acc[2], 0, 0, 0); \
        acc[3] = __builtin_amdgcn_mfma_f32_16x16x32_f16(af_, b3_, acc[3], 0, 0, 0); \
        acc[4] = __builtin_amdgcn_mfma_f32_16x16x32_f16(af_, b4_, acc[4], 0, 0, 0); \
        acc[5] = __builtin_amdgcn_mfma_f32_16x16x32_f16(af_, b5_, acc[5], 0, 0, 0); \
        acc[6] = __builtin_amdgcn_mfma_f32_16x16x32_f16(af_, b6_, acc[6], 0, 0, 0); \
        acc[7] = __builtin_amdgcn_mfma_f32_16x16x32_f16(af_, b7_, acc[7], 0, 0, 0); \
        acc[8] = __builtin_amdgcn_mfma_f32_16x16x32_f16(af_, b8_, acc[8], 0, 0, 0); \
        if ((KS) < 15) {                                                   \
            const _Float16* Bn_ = Bp + (size_t)((KS) + 1) * NTILE * 512;   \
            b0_ = *(const half8*)(Bn_);                                    \
            b1_ = *(const half8*)(Bn_ + 1 * 512);                          \
            b2_ = *(const half8*)(Bn_ + 2 * 512);                          \
            b3_ = *(const half8*)(Bn_ + 3 * 512);                          \
            b4_ = *(const half8*)(Bn_ + 4 * 512);                          \
            b5_ = *(const half8*)(Bn_ + 5 * 512);                          \
            b6_ = *(const half8*)(Bn_ + 6 * 512);                          \
            b7_ = *(const half8*)(Bn_ + 7 * 512);                          \
            b8_ = *(const half8*)(Bn_ + 8 * 512);                          \
            NL0 = *(const f32x4*)(A0 + ((KS) + 1) * 32);                   \
            NL1 = *(const f32x4*)(A0 + ((KS) + 1) * 32 + 4);               \
        }                                                                  \
        __syncthreads();                                                   \
    } while (0)

    STEP( 0, aC0, aC1, aN0, aN1);
    STEP( 1, aN0, aN1, aC0, aC1);
    STEP( 2, aC0, aC1, aN0, aN1);
    STEP( 3, aN0, aN1, aC0, aC1);
    STEP( 4, aC0, aC1, aN0, aN1);
    STEP( 5, aN0, aN1, aC0, aC1);
    STEP( 6, aC0, aC1, aN0, aN1);
    STEP( 7, aN0, aN1, aC0, aC1);
    STEP( 8, aC0, aC1, aN0, aN1);
    STEP( 9, aN0, aN1, aC0, aC1);
    STEP(10, aC0, aC1, aN0, aN1);
    STEP(11, aN0, aN1, aC0, aC1);
    STEP(12, aC0, aC1, aN0, aN1);
    STEP(13, aN0, aN1, aC0, aC1);
    STEP(14, aC0, aC1, aN0, aN1);
    STEP(15, aN0, aN1, aC0, aC1);
#undef STEP

    // C/D layout (measured m89/m91): col = lane&15, row = quad*4 + reg.
    #pragma unroll
    for (int nt = 0; nt < NTILE; nt++) {
        #pragma unroll
        for (int r = 0; r < 4; r++) {
            red[wave][quad * 4 + r][nt * 16 + low] = acc[nt][r];
        }
    }
    __syncthreads();

    // Epilogue: threads 0..127 -> (row = tid>>3 in [0,16), top = tid&7).
    if (tid < 128) {
        const int row = tid >> 3;
        const int top = tid & 7;

        float zt = top_b[top];
        #pragma unroll
        for (int w = 0; w < 4; w++) zt += red[w][row][top];
        const float sig = 1.0f / (1.0f + __expf(-zt));

        float z[16];
        float zmax = -1e30f;
        #pragma unroll
        for (int c = 0; c < 16; c++) {
            float v = bot_b[top * 16 + c];
            #pragma unroll
            for (int w = 0; w < 4; w++) v += red[w][row][8 + top * 16 + c];
            z[c] = v;
            zmax = fmaxf(zmax, v);
        }
        float s = 0.0f;
        #pragma unroll
        for (int c = 0; c < 16; c++) { z[c] = __expf(z[c] - zmax); s += z[c]; }
        const float scale = sig / s;

        float* o = out + (row0 + row) * 128 + top * 16;
        #pragma unroll
        for (int c = 0; c < 16; c += 4) {
            f32x4 v = { z[c] * scale, z[c+1] * scale, z[c+2] * scale, z[c+3] * scale };
            *(f32x4*)(o + c) = v;
        }
    }
}

extern "C" void kernel_launch(void* const* d_in, const int* in_sizes, int n_in,
                              void* d_out, int out_size, void* d_ws, size_t ws_size,
                              hipStream_t stream) {
    const float* feat  = (const float*)d_in[0];   // (16384, 2048)
    const float* topW  = (const float*)d_in[1];   // (8, 2048)
    const float* topB  = (const float*)d_in[2];   // (8,)
    const float* botW  = (const float*)d_in[3];   // (8, 2048, 16)
    const float* botB  = (const float*)d_in[4];   // (8, 16)
    float* out = (float*)d_out;                   // (16384, 128)
    _Float16* Bsw = (_Float16*)d_ws;              // 144*2048 fp16 = 576 KB swizzled

    prep_weights<<<(4 * 16 * NTILE * 64 + 255) / 256, 256, 0, stream>>>(topW, botW, Bsw);
    hc_fused<<<16384 / M_ROWS, 256, 0, stream>>>(feat, Bsw, topB, botB, out);
}